// Round 3
// baseline (151.211 us; speedup 1.0000x reference)
//
#include <hip/hip_runtime.h>
#include <hip/hip_bf16.h>
#include <math.h>

typedef __bf16 bf16;
typedef __attribute__((ext_vector_type(8))) __bf16 bf16x8;
typedef __attribute__((ext_vector_type(4))) __bf16 bf16x4;
typedef __attribute__((ext_vector_type(4))) short s16x4;
typedef __attribute__((ext_vector_type(4))) float f32x4;

#define T_SEQ 2048

static __device__ __forceinline__ float fast_exp2(float x) {
#if __has_builtin(__builtin_amdgcn_exp2f)
    return __builtin_amdgcn_exp2f(x);
#else
    return __expf(x * 0.69314718f);
#endif
}

// ---------------- fp32 -> bf16 elementwise convert (x) ----------------
__global__ void convert_kernel(const float* __restrict__ x, bf16* __restrict__ xb, int n4)
{
    int i = blockIdx.x * blockDim.x + threadIdx.x;
    int stride = gridDim.x * blockDim.x;
    for (; i < n4; i += stride) {
        f32x4 v = ((const f32x4*)x)[i];
        bf16x4 o;
        o[0] = (bf16)v[0]; o[1] = (bf16)v[1]; o[2] = (bf16)v[2]; o[3] = (bf16)v[3];
        ((bf16x4*)xb)[i] = o;
    }
}

// ---------------- tiled transpose + convert: W[K][N] f32 -> Wt[N][K] bf16 ----------------
__global__ __launch_bounds__(256) void transpose_conv_kernel(
    const float* __restrict__ W, bf16* __restrict__ Wt, int K, int N)
{
    __shared__ float tile[32][33];
    int tx = threadIdx.x & 31, ty = threadIdx.x >> 5;       // ty 0..7
    int n0 = blockIdx.x * 32, k0 = blockIdx.y * 32;
#pragma unroll
    for (int j = 0; j < 4; ++j)
        tile[ty + j * 8][tx] = W[(size_t)(k0 + ty + j * 8) * N + n0 + tx];
    __syncthreads();
#pragma unroll
    for (int j = 0; j < 4; ++j)
        Wt[(size_t)(n0 + ty + j * 8) * K + k0 + tx] = (bf16)tile[tx][ty + j * 8];
}

// ---------------- V pre-transpose: Vt[bh][d][t] = qkv[b][t][2048 + h*64 + d] ----------------
__global__ __launch_bounds__(256) void vtrans_kernel(
    const bf16* __restrict__ qkv, bf16* __restrict__ Vt)
{
    __shared__ bf16 tile[64][72];
    const int tid = threadIdx.x;
    const int bh = blockIdx.y, b = bh >> 4, h = bh & 15;
    const int t0 = blockIdx.x * 64;
    const size_t base = (size_t)b * T_SEQ * 3072 + 2048 + h * 64;
    const int r = tid >> 3, c = (tid & 7) * 8;
    *(bf16x8*)&tile[r][c]      = *(const bf16x8*)&qkv[base + (size_t)(t0 + r) * 3072 + c];
    *(bf16x8*)&tile[r + 32][c] = *(const bf16x8*)&qkv[base + (size_t)(t0 + r + 32) * 3072 + c];
    __syncthreads();
    bf16x8 o0, o1;
#pragma unroll
    for (int j = 0; j < 8; ++j) { o0[j] = tile[c + j][r]; o1[j] = tile[c + j][r + 32]; }
    *(bf16x8*)&Vt[((size_t)bh * 64 + r) * T_SEQ + t0 + c] = o0;
    *(bf16x8*)&Vt[((size_t)bh * 64 + r + 32) * T_SEQ + t0 + c] = o1;
}

// ---------------- GEMM: C[M][N] = A[M][K] * Bt[N][K]^T + bias ----------------
template<int OUT_BF16>
__global__ __launch_bounds__(256) void gemm_bias_kernel(
    const bf16* __restrict__ A, const bf16* __restrict__ Bt,
    const float* __restrict__ bias, void* __restrict__ Cout,
    int M, int N, int K)
{
    __shared__ bf16 As[128][72];
    __shared__ bf16 Bs[128][72];
    const int tid = threadIdx.x;
    const int lane = tid & 63, wid = tid >> 6;
    const int wm = wid >> 1, wn = wid & 1;
    const int m0 = blockIdx.y * 128, n0 = blockIdx.x * 128;
    const int l15 = lane & 15, l4 = lane >> 4;

    f32x4 acc[4][4] = {};

    for (int kt = 0; kt < K; kt += 64) {
#pragma unroll
        for (int it = 0; it < 4; ++it) {
            int ch = tid + it * 256;
            int r = ch >> 3, c = (ch & 7) * 8;
            *(bf16x8*)&As[r][c] = *(const bf16x8*)&A[(size_t)(m0 + r) * K + kt + c];
            *(bf16x8*)&Bs[r][c] = *(const bf16x8*)&Bt[(size_t)(n0 + r) * K + kt + c];
        }
        __syncthreads();
#pragma unroll
        for (int kk = 0; kk < 2; ++kk) {
            bf16x8 af[4], bfr[4];
#pragma unroll
            for (int mi = 0; mi < 4; ++mi)
                af[mi] = *(const bf16x8*)&As[wm * 64 + mi * 16 + l15][kk * 32 + l4 * 8];
#pragma unroll
            for (int ni = 0; ni < 4; ++ni)
                bfr[ni] = *(const bf16x8*)&Bs[wn * 64 + ni * 16 + l15][kk * 32 + l4 * 8];
#pragma unroll
            for (int mi = 0; mi < 4; ++mi)
#pragma unroll
                for (int ni = 0; ni < 4; ++ni)
                    acc[mi][ni] = __builtin_amdgcn_mfma_f32_16x16x32_bf16(
                        af[mi], bfr[ni], acc[mi][ni], 0, 0, 0);
        }
        __syncthreads();
    }
#pragma unroll
    for (int mi = 0; mi < 4; ++mi) {
#pragma unroll
        for (int ni = 0; ni < 4; ++ni) {
            int col = n0 + wn * 64 + ni * 16 + l15;
            float bv = bias[col];
#pragma unroll
            for (int r = 0; r < 4; ++r) {
                int row = m0 + wm * 64 + mi * 16 + l4 * 4 + r;
                float v = acc[mi][ni][r] + bv;
                if (OUT_BF16) ((bf16*)Cout)[(size_t)row * N + col] = (bf16)v;
                else          ((float*)Cout)[(size_t)row * N + col] = v;
            }
        }
    }
}

// ---------------- causal flash attention (fold-balanced, 2 waves x 32 q-rows) ----------------
// qkv: [B*T, 3072] bf16. Vt: [bh][64][T] bf16. attb: [B*T, 1024] bf16.
// grid (32 bh, 16 fold): block = 64 q-rows (q-tiles fp and 31-fp sequentially),
// exactly 33 k-tile iterations per block. Each wave: 32 q-rows (2 x 16-col frags).
// LDS K/V tile shared by only 2 waves -> half the LDS read volume per MFMA FLOP.
__global__ __launch_bounds__(128) void attn_kernel(
    const bf16* __restrict__ qkv, const bf16* __restrict__ Vt, bf16* __restrict__ attb)
{
    __shared__ bf16 Ks[64][72];
    __shared__ bf16 Vs[64][72];
    const int tid = threadIdx.x, lane = tid & 63, wid = tid >> 6;   // wid 0..1
    const int bh = blockIdx.x, b = bh >> 4, h = bh & 15;
    const int fp = blockIdx.y;
    const int l15 = lane & 15, l4 = lane >> 4;
    const size_t base = (size_t)b * T_SEQ * 3072;
    const int koff = 1024 + h * 64;
    const size_t vtb = (size_t)bh * 64 * T_SEQ;
    const int kr = tid >> 1, kc = (tid & 1) * 32;   // staging: 64 rows x 64 cols, 32 bf16/thread

    for (int pass = 0; pass < 2; ++pass) {
        const int iq = pass ? 31 - fp : fp;         // 64-row q-tile index
        const int q0 = iq * 64 + wid * 32;
        const int nt = iq + 1;

        bf16x8 Qf[2][2];
#pragma unroll
        for (int qf = 0; qf < 2; ++qf)
#pragma unroll
            for (int dh = 0; dh < 2; ++dh)
                Qf[qf][dh] = *(const bf16x8*)&qkv[base + (size_t)(q0 + qf * 16 + l15) * 3072
                                                 + h * 64 + dh * 32 + l4 * 8];

        f32x4 Oacc[4][2] = {};
        float m_run[2] = { -1e30f, -1e30f };
        float l_run[2] = { 0.f, 0.f };

        // prologue: prefetch tile 0 into regs
        bf16x8 kreg[4], vreg[4];
#pragma unroll
        for (int j = 0; j < 4; ++j) {
            kreg[j] = *(const bf16x8*)&qkv[base + (size_t)kr * 3072 + koff + kc + j * 8];
            vreg[j] = *(const bf16x8*)&Vt[vtb + (size_t)kr * T_SEQ + kc + j * 8];
        }

        for (int t = 0; t < nt; ++t) {
            __syncthreads();                        // prev-tile reads done
#pragma unroll
            for (int j = 0; j < 4; ++j) {
                *(bf16x8*)&Ks[kr][kc + j * 8] = kreg[j];
                *(bf16x8*)&Vs[kr][kc + j * 8] = vreg[j];
            }
            __syncthreads();                        // LDS ready
            if (t + 1 < nt) {                       // prefetch next tile (hides HBM/L2 latency)
                const int k1 = (t + 1) * 64;
#pragma unroll
                for (int j = 0; j < 4; ++j) {
                    kreg[j] = *(const bf16x8*)&qkv[base + (size_t)(k1 + kr) * 3072 + koff + kc + j * 8];
                    vreg[j] = *(const bf16x8*)&Vt[vtb + (size_t)kr * T_SEQ + k1 + kc + j * 8];
                }
            }
            // S^T = K . Q  (raw, unscaled)
            f32x4 S[4][2] = {};
#pragma unroll
            for (int dh = 0; dh < 2; ++dh)
#pragma unroll
                for (int kf = 0; kf < 4; ++kf) {
                    bf16x8 kfr = *(const bf16x8*)&Ks[kf * 16 + l15][dh * 32 + l4 * 8];
#pragma unroll
                    for (int qf = 0; qf < 2; ++qf)
                        S[kf][qf] = __builtin_amdgcn_mfma_f32_16x16x32_bf16(
                            kfr, Qf[qf][dh], S[kf][qf], 0, 0, 0);
                }
            const int diag = (t == nt - 1);
            s16x4 Pb[4][2];
#pragma unroll
            for (int qf = 0; qf < 2; ++qf) {
                float pmax = -3.0e38f;
                if (diag) {
                    const int qq = wid * 32 + qf * 16 + l15;   // local q within 64-tile
#pragma unroll
                    for (int kf = 0; kf < 4; ++kf)
#pragma unroll
                        for (int r = 0; r < 4; ++r) {
                            if (kf * 16 + l4 * 4 + r > qq) S[kf][qf][r] = -3.0e38f;
                            pmax = fmaxf(pmax, S[kf][qf][r]);
                        }
                } else {
#pragma unroll
                    for (int kf = 0; kf < 4; ++kf)
#pragma unroll
                        for (int r = 0; r < 4; ++r) pmax = fmaxf(pmax, S[kf][qf][r]);
                }
                pmax = fmaxf(pmax, __shfl_xor(pmax, 16));
                pmax = fmaxf(pmax, __shfl_xor(pmax, 32));
                // defer-rescale: raw-domain threshold 64 == 8 in score domain
                if (!__all(pmax - m_run[qf] <= 64.f)) {
                    float mnew = fmaxf(m_run[qf], pmax);
                    float alpha = fast_exp2((m_run[qf] - mnew) * 0.18033688f);
                    m_run[qf] = mnew;
                    l_run[qf] *= alpha;
#pragma unroll
                    for (int df = 0; df < 4; ++df) Oacc[df][qf] *= alpha;
                }
                float lsum = 0.f;
#pragma unroll
                for (int kf = 0; kf < 4; ++kf)
#pragma unroll
                    for (int r = 0; r < 4; ++r) {
                        float p = fast_exp2((S[kf][qf][r] - m_run[qf]) * 0.18033688f);
                        lsum += p;
                        Pb[kf][qf][r] = __builtin_bit_cast(short, (bf16)p);
                    }
                lsum += __shfl_xor(lsum, 16);
                lsum += __shfl_xor(lsum, 32);
                l_run[qf] += lsum;
            }
            // out^T += V^T * P
#pragma unroll
            for (int kf = 0; kf < 4; ++kf)
#pragma unroll
                for (int df = 0; df < 4; ++df) {
                    bf16x4 av = *(const bf16x4*)&Vs[df * 16 + l15][kf * 16 + l4 * 4];
                    s16x4 avs = __builtin_bit_cast(s16x4, av);
#pragma unroll
                    for (int qf = 0; qf < 2; ++qf)
                        Oacc[df][qf] = __builtin_amdgcn_mfma_f32_16x16x16bf16_1k(
                            avs, Pb[kf][qf], Oacc[df][qf], 0, 0, 0);
                }
        }
        // epilogue
#pragma unroll
        for (int qf = 0; qf < 2; ++qf) {
            float inv = 1.f / l_run[qf];
            const int qrow = q0 + qf * 16 + l15;
#pragma unroll
            for (int df = 0; df < 4; ++df) {
                bf16x4 o;
#pragma unroll
                for (int r = 0; r < 4; ++r) o[r] = (bf16)(Oacc[df][qf][r] * inv);
                *(bf16x4*)&attb[((size_t)b * T_SEQ + qrow) * 1024 + h * 64 + df * 16 + l4 * 4] = o;
            }
        }
    }
}

// ---------------- launcher ----------------
extern "C" void kernel_launch(void* const* d_in, const int* in_sizes, int n_in,
                              void* d_out, int out_size, void* d_ws, size_t ws_size,
                              hipStream_t stream)
{
    const float* x    = (const float*)d_in[0];   // [2,2048,1024]
    const float* Wqkv = (const float*)d_in[1];   // [1024,3072]
    const float* bqkv = (const float*)d_in[2];   // [3072]
    const float* Wout = (const float*)d_in[3];   // [1024,1024]
    const float* bout = (const float*)d_in[4];   // [1024]
    float* out = (float*)d_out;                  // [2,2048,1024] f32

    char* ws = (char*)d_ws;
    bf16* xb    = (bf16*)(ws);                    // 8 MB (dead after gemm1)
    bf16* Vt    = (bf16*)(ws);                    // 8 MB, reuses xb region
    bf16* Wqkvt = (bf16*)(ws + (8ull  << 20));    // 6 MB
    bf16* Woutt = (bf16*)(ws + (14ull << 20));    // 2 MB
    bf16* qkvb  = (bf16*)(ws + (16ull << 20));    // 24 MB
    bf16* attb  = (bf16*)(ws + (40ull << 20));    // 8 MB

    convert_kernel<<<dim3(2048), dim3(256), 0, stream>>>(x, xb, (4096 * 1024) / 4);
    transpose_conv_kernel<<<dim3(96, 32), dim3(256), 0, stream>>>(Wqkv, Wqkvt, 1024, 3072);
    transpose_conv_kernel<<<dim3(32, 32), dim3(256), 0, stream>>>(Wout, Woutt, 1024, 1024);
    gemm_bias_kernel<1><<<dim3(24, 32), dim3(256), 0, stream>>>(
        xb, Wqkvt, bqkv, (void*)qkvb, 4096, 3072, 1024);
    vtrans_kernel<<<dim3(32, 32), dim3(256), 0, stream>>>(qkvb, Vt);
    attn_kernel<<<dim3(32, 16), dim3(128), 0, stream>>>(qkvb, Vt, attb);
    gemm_bias_kernel<0><<<dim3(8, 32), dim3(256), 0, stream>>>(
        attb, Woutt, bout, (void*)out, 4096, 1024, 1024);
}

// Round 4
// 135.460 us; speedup vs baseline: 1.1163x; 1.1163x over previous
//
#include <hip/hip_runtime.h>
#include <hip/hip_bf16.h>
#include <math.h>

typedef __bf16 bf16;
typedef __attribute__((ext_vector_type(8))) __bf16 bf16x8;
typedef __attribute__((ext_vector_type(4))) __bf16 bf16x4;
typedef __attribute__((ext_vector_type(4))) short s16x4;
typedef __attribute__((ext_vector_type(4))) float f32x4;

#define T_SEQ 2048

static __device__ __forceinline__ float fast_exp2(float x) {
#if __has_builtin(__builtin_amdgcn_exp2f)
    return __builtin_amdgcn_exp2f(x);
#else
    return __expf(x * 0.69314718f);
#endif
}

// async global->LDS, 16B per lane (HW: wave-uniform LDS base + lane*16)
static __device__ __forceinline__ void gload_lds16(const bf16* g, bf16* l) {
    __builtin_amdgcn_global_load_lds((const __attribute__((address_space(1))) void*)g,
                                     (__attribute__((address_space(3))) void*)l, 16, 0, 0);
}

// XOR swizzle within a 128B row: spreads 8 rows across 8 16B bank-slots
static __device__ __forceinline__ int swz(int row, int colb) {
    return row * 128 + (colb ^ ((row & 7) << 4));
}

// ---------------- fp32 -> bf16 elementwise convert (x) ----------------
__global__ void convert_kernel(const float* __restrict__ x, bf16* __restrict__ xb, int n4)
{
    int i = blockIdx.x * blockDim.x + threadIdx.x;
    int stride = gridDim.x * blockDim.x;
    for (; i < n4; i += stride) {
        f32x4 v = ((const f32x4*)x)[i];
        bf16x4 o;
        o[0] = (bf16)v[0]; o[1] = (bf16)v[1]; o[2] = (bf16)v[2]; o[3] = (bf16)v[3];
        ((bf16x4*)xb)[i] = o;
    }
}

// ---------------- tiled transpose + convert: W[K][N] f32 -> Wt[N][K] bf16 ----------------
__global__ __launch_bounds__(256) void transpose_conv_kernel(
    const float* __restrict__ W, bf16* __restrict__ Wt, int K, int N)
{
    __shared__ float tile[32][33];
    int tx = threadIdx.x & 31, ty = threadIdx.x >> 5;       // ty 0..7
    int n0 = blockIdx.x * 32, k0 = blockIdx.y * 32;
#pragma unroll
    for (int j = 0; j < 4; ++j)
        tile[ty + j * 8][tx] = W[(size_t)(k0 + ty + j * 8) * N + n0 + tx];
    __syncthreads();
#pragma unroll
    for (int j = 0; j < 4; ++j)
        Wt[(size_t)(n0 + ty + j * 8) * K + k0 + tx] = (bf16)tile[tx][ty + j * 8];
}

// ---------------- V pre-transpose: Vt[bh][d][t] = qkv[b][t][2048 + h*64 + d] ----------------
__global__ __launch_bounds__(256) void vtrans_kernel(
    const bf16* __restrict__ qkv, bf16* __restrict__ Vt)
{
    __shared__ bf16 tile[64][72];
    const int tid = threadIdx.x;
    const int bh = blockIdx.y, b = bh >> 4, h = bh & 15;
    const int t0 = blockIdx.x * 64;
    const size_t base = (size_t)b * T_SEQ * 3072 + 2048 + h * 64;
    const int r = tid >> 3, c = (tid & 7) * 8;
    *(bf16x8*)&tile[r][c]      = *(const bf16x8*)&qkv[base + (size_t)(t0 + r) * 3072 + c];
    *(bf16x8*)&tile[r + 32][c] = *(const bf16x8*)&qkv[base + (size_t)(t0 + r + 32) * 3072 + c];
    __syncthreads();
    bf16x8 o0, o1;
#pragma unroll
    for (int j = 0; j < 8; ++j) { o0[j] = tile[c + j][r]; o1[j] = tile[c + j][r + 32]; }
    *(bf16x8*)&Vt[((size_t)bh * 64 + r) * T_SEQ + t0 + c] = o0;
    *(bf16x8*)&Vt[((size_t)bh * 64 + r + 32) * T_SEQ + t0 + c] = o1;
}

// ---------------- GEMM: C[M][N] = A[M][K] * Bt[N][K]^T + bias ----------------
// m97-style: global_load_lds width-16 staging into linear LDS, BK=64.
template<int OUT_BF16>
__global__ __launch_bounds__(256) void gemm_bias_kernel(
    const bf16* __restrict__ A, const bf16* __restrict__ Bt,
    const float* __restrict__ bias, void* __restrict__ Cout,
    int M, int N, int K)
{
    __shared__ bf16 As[128][64];
    __shared__ bf16 Bs[128][64];
    const int tid = threadIdx.x;
    const int lane = tid & 63, wid = tid >> 6;
    const int wm = wid >> 1, wn = wid & 1;
    const int m0 = blockIdx.y * 128, n0 = blockIdx.x * 128;
    const int l15 = lane & 15, l4 = lane >> 4;

    f32x4 acc[4][4] = {};

    for (int kt = 0; kt < K; kt += 64) {
        // stage: 128 rows x 64 cols = 1024 x 16B chunks per matrix
#pragma unroll
        for (int it = 0; it < 4; ++it) {
            int ch = (wid * 4 + it) * 64 + lane;
            int r = ch >> 3, c = (ch & 7) * 8;
            gload_lds16(&A[(size_t)(m0 + r) * K + kt + c], &As[0][0] + (wid * 4 + it) * 512);
            gload_lds16(&Bt[(size_t)(n0 + r) * K + kt + c], &Bs[0][0] + (wid * 4 + it) * 512);
        }
        __syncthreads();
#pragma unroll
        for (int kk = 0; kk < 2; ++kk) {
            bf16x8 af[4], bfr[4];
#pragma unroll
            for (int mi = 0; mi < 4; ++mi)
                af[mi] = *(const bf16x8*)&As[wm * 64 + mi * 16 + l15][kk * 32 + l4 * 8];
#pragma unroll
            for (int ni = 0; ni < 4; ++ni)
                bfr[ni] = *(const bf16x8*)&Bs[wn * 64 + ni * 16 + l15][kk * 32 + l4 * 8];
#pragma unroll
            for (int mi = 0; mi < 4; ++mi)
#pragma unroll
                for (int ni = 0; ni < 4; ++ni)
                    acc[mi][ni] = __builtin_amdgcn_mfma_f32_16x16x32_bf16(
                        af[mi], bfr[ni], acc[mi][ni], 0, 0, 0);
        }
        __syncthreads();
    }
#pragma unroll
    for (int mi = 0; mi < 4; ++mi) {
#pragma unroll
        for (int ni = 0; ni < 4; ++ni) {
            int col = n0 + wn * 64 + ni * 16 + l15;
            float bv = bias[col];
#pragma unroll
            for (int r = 0; r < 4; ++r) {
                int row = m0 + wm * 64 + mi * 16 + l4 * 4 + r;
                float v = acc[mi][ni][r] + bv;
                if (OUT_BF16) ((bf16*)Cout)[(size_t)row * N + col] = (bf16)v;
                else          ((float*)Cout)[(size_t)row * N + col] = v;
            }
        }
    }
}

// ---------------- causal flash attention ----------------
// Block: 256 threads = 4 waves = 2 q-groups (32 rows) x 2 k-parities.
// Tile pair (2u, 2u+1) double-buffered in swizzled LDS; wave parity p computes
// tile 2u+p. End-of-block (m,l,O) merge across parities via LDS.
// Grid: 1024 blocks, longest-first (LPT) for dynamic balance.
__global__ __launch_bounds__(256, 3) void attn_kernel(
    const bf16* __restrict__ qkv, const bf16* __restrict__ Vt, bf16* __restrict__ attb)
{
    __shared__ __align__(16) char smem[32768];   // K bufs @0, V bufs @16384
    const int tid = threadIdx.x, lane = tid & 63, wid = tid >> 6;
    const int qg = wid >> 1, par = wid & 1;
    const int bid = blockIdx.x;
    const int iq = 31 - (bid >> 5);              // longest q-tiles dispatch first
    const int bh = bid & 31, b = bh >> 4, h = bh & 15;
    const int nt = iq + 1, npairs = (nt + 1) >> 1;
    const int l15 = lane & 15, l4 = lane >> 4;
    const size_t base = (size_t)b * T_SEQ * 3072;
    const int koff = 1024 + h * 64;
    const size_t vtb = (size_t)bh * 64 * T_SEQ;
    const int sr = tid >> 2, sq4 = tid & 3;      // staging: row, 32B-quarter

    const int q0 = iq * 64 + qg * 32;
    bf16x8 Qf[2][2];
#pragma unroll
    for (int qf = 0; qf < 2; ++qf)
#pragma unroll
        for (int dh = 0; dh < 2; ++dh)
            Qf[qf][dh] = *(const bf16x8*)&qkv[base + (size_t)(q0 + qf * 16 + l15) * 3072
                                             + h * 64 + dh * 32 + l4 * 8];

    f32x4 Oacc[4][2] = {};
    float m_run[2] = { -1e30f, -1e30f };
    float l_run[2] = { 0.f, 0.f };

    bf16x8 kreg[2][2], vreg[2][2];
    {   // prefetch pair 0
        const int pb = 0;
#pragma unroll
        for (int p = 0; p < 2; ++p)
#pragma unroll
            for (int j = 0; j < 2; ++j) {
                kreg[p][j] = *(const bf16x8*)&qkv[base + (size_t)(pb + p * 64 + sr) * 3072
                                                 + koff + sq4 * 16 + j * 8];
                vreg[p][j] = *(const bf16x8*)&Vt[vtb + (size_t)sr * T_SEQ + pb + p * 64 + sq4 * 16 + j * 8];
            }
    }

    for (int u = 0; u < npairs; ++u) {
        __syncthreads();                          // prev-tile reads done
#pragma unroll
        for (int p = 0; p < 2; ++p) {
            char* Kp = smem + p * 8192;
            char* Vp = smem + 16384 + p * 8192;
#pragma unroll
            for (int j = 0; j < 2; ++j) {
                const int byte = swz(sr, sq4 * 32 + j * 16);
                *(bf16x8*)(Kp + byte) = kreg[p][j];
                *(bf16x8*)(Vp + byte) = vreg[p][j];
            }
        }
        __syncthreads();                          // LDS ready
        if (u + 1 < npairs) {                     // prefetch next pair
            const int pb = (u + 1) * 128;
#pragma unroll
            for (int p = 0; p < 2; ++p)
#pragma unroll
                for (int j = 0; j < 2; ++j) {
                    kreg[p][j] = *(const bf16x8*)&qkv[base + (size_t)(pb + p * 64 + sr) * 3072
                                                     + koff + sq4 * 16 + j * 8];
                    vreg[p][j] = *(const bf16x8*)&Vt[vtb + (size_t)sr * T_SEQ + pb + p * 64 + sq4 * 16 + j * 8];
                }
        }
        const int t = 2 * u + par;
        if (t < nt) {
            const char* Kc = smem + par * 8192;
            const char* Vc = smem + 16384 + par * 8192;
            // S^T = K . Q  (raw, unscaled)
            f32x4 S[4][2] = {};
#pragma unroll
            for (int dh = 0; dh < 2; ++dh)
#pragma unroll
                for (int kf = 0; kf < 4; ++kf) {
                    bf16x8 kfr = *(const bf16x8*)(Kc + swz(kf * 16 + l15, dh * 64 + l4 * 16));
#pragma unroll
                    for (int qf = 0; qf < 2; ++qf)
                        S[kf][qf] = __builtin_amdgcn_mfma_f32_16x16x32_bf16(
                            kfr, Qf[qf][dh], S[kf][qf], 0, 0, 0);
                }
            const int diag = (t == nt - 1);
            s16x4 Pb[4][2];
#pragma unroll
            for (int qf = 0; qf < 2; ++qf) {
                float pmax = -3.0e38f;
                if (diag) {
                    const int qq = qg * 32 + qf * 16 + l15;    // tile-local q
#pragma unroll
                    for (int kf = 0; kf < 4; ++kf)
#pragma unroll
                        for (int r = 0; r < 4; ++r) {
                            if (kf * 16 + l4 * 4 + r > qq) S[kf][qf][r] = -3.0e38f;
                            pmax = fmaxf(pmax, S[kf][qf][r]);
                        }
                } else {
#pragma unroll
                    for (int kf = 0; kf < 4; ++kf)
#pragma unroll
                        for (int r = 0; r < 4; ++r) pmax = fmaxf(pmax, S[kf][qf][r]);
                }
                pmax = fmaxf(pmax, __shfl_xor(pmax, 16));
                pmax = fmaxf(pmax, __shfl_xor(pmax, 32));
                if (!__all(pmax - m_run[qf] <= 64.f)) {        // defer-rescale (8 in score dom.)
                    float mnew = fmaxf(m_run[qf], pmax);
                    float alpha = fast_exp2((m_run[qf] - mnew) * 0.18033688f);
                    m_run[qf] = mnew;
                    l_run[qf] *= alpha;
#pragma unroll
                    for (int df = 0; df < 4; ++df) Oacc[df][qf] *= alpha;
                }
                float lsum = 0.f;
#pragma unroll
                for (int kf = 0; kf < 4; ++kf)
#pragma unroll
                    for (int r = 0; r < 4; ++r) {
                        float p = fast_exp2((S[kf][qf][r] - m_run[qf]) * 0.18033688f);
                        lsum += p;
                        Pb[kf][qf][r] = __builtin_bit_cast(short, (bf16)p);
                    }
                lsum += __shfl_xor(lsum, 16);
                lsum += __shfl_xor(lsum, 32);
                l_run[qf] += lsum;
            }
            // out^T += V^T * P
#pragma unroll
            for (int kf = 0; kf < 4; ++kf)
#pragma unroll
                for (int df = 0; df < 4; ++df) {
                    bf16x4 av = *(const bf16x4*)(Vc + swz(df * 16 + l15, kf * 32 + l4 * 8));
                    s16x4 avs = __builtin_bit_cast(s16x4, av);
#pragma unroll
                    for (int qf = 0; qf < 2; ++qf)
                        Oacc[df][qf] = __builtin_amdgcn_mfma_f32_16x16x16bf16_1k(
                            avs, Pb[kf][qf], Oacc[df][qf], 0, 0, 0);
                }
        }
    }

    // ---- cross-parity merge (reuse LDS) ----
    float* cbuf = (float*)smem;                  // 128 lanes x 36 floats = 18KB
    __syncthreads();
    if (par == 1) {
        float* p = cbuf + (qg * 64 + lane) * 36;
#pragma unroll
        for (int df = 0; df < 4; ++df)
#pragma unroll
            for (int qf = 0; qf < 2; ++qf)
                *(f32x4*)(p + (df * 2 + qf) * 4) = Oacc[df][qf];
        p[32] = m_run[0]; p[33] = m_run[1]; p[34] = l_run[0]; p[35] = l_run[1];
    }
    __syncthreads();
    if (par == 0) {
        const float* p = cbuf + (qg * 64 + lane) * 36;
#pragma unroll
        for (int qf = 0; qf < 2; ++qf) {
            float m1 = p[32 + qf], l1 = p[34 + qf];
            float m = fmaxf(m_run[qf], m1);
            float a0 = fast_exp2((m_run[qf] - m) * 0.18033688f);
            float a1 = fast_exp2((m1 - m) * 0.18033688f);
            float inv = 1.f / (l_run[qf] * a0 + l1 * a1);
            const int qrow = q0 + qf * 16 + l15;
#pragma unroll
            for (int df = 0; df < 4; ++df) {
                const float* po = p + (df * 2 + qf) * 4;
                bf16x4 o;
#pragma unroll
                for (int r = 0; r < 4; ++r)
                    o[r] = (bf16)((Oacc[df][qf][r] * a0 + po[r] * a1) * inv);
                *(bf16x4*)&attb[((size_t)b * T_SEQ + qrow) * 1024 + h * 64 + df * 16 + l4 * 4] = o;
            }
        }
    }
}

// ---------------- launcher ----------------
extern "C" void kernel_launch(void* const* d_in, const int* in_sizes, int n_in,
                              void* d_out, int out_size, void* d_ws, size_t ws_size,
                              hipStream_t stream)
{
    const float* x    = (const float*)d_in[0];   // [2,2048,1024]
    const float* Wqkv = (const float*)d_in[1];   // [1024,3072]
    const float* bqkv = (const float*)d_in[2];   // [3072]
    const float* Wout = (const float*)d_in[3];   // [1024,1024]
    const float* bout = (const float*)d_in[4];   // [1024]
    float* out = (float*)d_out;                  // [2,2048,1024] f32

    char* ws = (char*)d_ws;
    bf16* xb    = (bf16*)(ws);                    // 8 MB (dead after gemm1)
    bf16* Vt    = (bf16*)(ws);                    // 8 MB, reuses xb region
    bf16* Wqkvt = (bf16*)(ws + (8ull  << 20));    // 6 MB
    bf16* Woutt = (bf16*)(ws + (14ull << 20));    // 2 MB
    bf16* qkvb  = (bf16*)(ws + (16ull << 20));    // 24 MB
    bf16* attb  = (bf16*)(ws + (40ull << 20));    // 8 MB

    convert_kernel<<<dim3(2048), dim3(256), 0, stream>>>(x, xb, (4096 * 1024) / 4);
    transpose_conv_kernel<<<dim3(96, 32), dim3(256), 0, stream>>>(Wqkv, Wqkvt, 1024, 3072);
    transpose_conv_kernel<<<dim3(32, 32), dim3(256), 0, stream>>>(Wout, Woutt, 1024, 1024);
    gemm_bias_kernel<1><<<dim3(24, 32), dim3(256), 0, stream>>>(
        xb, Wqkvt, bqkv, (void*)qkvb, 4096, 3072, 1024);
    vtrans_kernel<<<dim3(32, 32), dim3(256), 0, stream>>>(qkvb, Vt);
    attn_kernel<<<dim3(1024), dim3(256), 0, stream>>>(qkvb, Vt, attb);
    gemm_bias_kernel<0><<<dim3(8, 32), dim3(256), 0, stream>>>(
        attb, Woutt, bout, (void*)out, 4096, 1024, 1024);
}

// Round 5
// 105.071 us; speedup vs baseline: 1.4391x; 1.2892x over previous
//
#include <hip/hip_runtime.h>
#include <hip/hip_bf16.h>
#include <math.h>

typedef __bf16 bf16;
typedef __attribute__((ext_vector_type(8))) __bf16 bf16x8;
typedef __attribute__((ext_vector_type(4))) __bf16 bf16x4;
typedef __attribute__((ext_vector_type(4))) short s16x4;
typedef __attribute__((ext_vector_type(4))) float f32x4;

#define T_SEQ 2048

static __device__ __forceinline__ float fast_exp2(float x) {
#if __has_builtin(__builtin_amdgcn_exp2f)
    return __builtin_amdgcn_exp2f(x);
#else
    return __expf(x * 0.69314718f);
#endif
}

// async global->LDS, 16B per lane (HW: wave-uniform LDS base + lane*16)
static __device__ __forceinline__ void gload_lds16(const bf16* g, bf16* l) {
    __builtin_amdgcn_global_load_lds((const __attribute__((address_space(1))) void*)g,
                                     (__attribute__((address_space(3))) void*)l, 16, 0, 0);
}

// XOR swizzle within a 128B row: spreads 8 rows across 8 16B bank-slots
static __device__ __forceinline__ int swz(int row, int colb) {
    return row * 128 + (colb ^ ((row & 7) << 4));
}

// ---------------- fp32 -> bf16 elementwise convert (x) ----------------
__global__ void convert_kernel(const float* __restrict__ x, bf16* __restrict__ xb, int n4)
{
    int i = blockIdx.x * blockDim.x + threadIdx.x;
    int stride = gridDim.x * blockDim.x;
    for (; i < n4; i += stride) {
        f32x4 v = ((const f32x4*)x)[i];
        bf16x4 o;
        o[0] = (bf16)v[0]; o[1] = (bf16)v[1]; o[2] = (bf16)v[2]; o[3] = (bf16)v[3];
        ((bf16x4*)xb)[i] = o;
    }
}

// ---------------- tiled transpose + convert: W[K][N] f32 -> Wt[N][K] bf16 ----------------
__global__ __launch_bounds__(256) void transpose_conv_kernel(
    const float* __restrict__ W, bf16* __restrict__ Wt, int K, int N)
{
    __shared__ float tile[32][33];
    int tx = threadIdx.x & 31, ty = threadIdx.x >> 5;       // ty 0..7
    int n0 = blockIdx.x * 32, k0 = blockIdx.y * 32;
#pragma unroll
    for (int j = 0; j < 4; ++j)
        tile[ty + j * 8][tx] = W[(size_t)(k0 + ty + j * 8) * N + n0 + tx];
    __syncthreads();
#pragma unroll
    for (int j = 0; j < 4; ++j)
        Wt[(size_t)(n0 + ty + j * 8) * K + k0 + tx] = (bf16)tile[tx][ty + j * 8];
}

// ---------------- V pre-transpose: Vt[bh][d][t] = qkv[b][t][2048 + h*64 + d] ----------------
__global__ __launch_bounds__(256) void vtrans_kernel(
    const bf16* __restrict__ qkv, bf16* __restrict__ Vt)
{
    __shared__ bf16 tile[64][72];
    const int tid = threadIdx.x;
    const int bh = blockIdx.y, b = bh >> 4, h = bh & 15;
    const int t0 = blockIdx.x * 64;
    const size_t base = (size_t)b * T_SEQ * 3072 + 2048 + h * 64;
    const int r = tid >> 3, c = (tid & 7) * 8;
    *(bf16x8*)&tile[r][c]      = *(const bf16x8*)&qkv[base + (size_t)(t0 + r) * 3072 + c];
    *(bf16x8*)&tile[r + 32][c] = *(const bf16x8*)&qkv[base + (size_t)(t0 + r + 32) * 3072 + c];
    __syncthreads();
    bf16x8 o0, o1;
#pragma unroll
    for (int j = 0; j < 8; ++j) { o0[j] = tile[c + j][r]; o1[j] = tile[c + j][r + 32]; }
    *(bf16x8*)&Vt[((size_t)bh * 64 + r) * T_SEQ + t0 + c] = o0;
    *(bf16x8*)&Vt[((size_t)bh * 64 + r + 32) * T_SEQ + t0 + c] = o1;
}

// ---------------- GEMM: C = A[M][K] * Bt[N][K]^T + bias ----------------
// Minimal-2-phase dbuf template (m248 shape): STAGE(next) -> COMPUTE(cur) ->
// vmcnt(0) + raw barrier, once per K-step. Pre-swizzled global source + swizzled
// ds_read (both-sides XOR). Grid sized to exactly 256 blocks, XCD-chunked.
template<int BM, int BN, int BLK, int WGN, int OUT_BF16>
__global__ __launch_bounds__(BLK, 2) void gemm2ph_kernel(
    const bf16* __restrict__ A, const bf16* __restrict__ Bt,
    const float* __restrict__ bias, void* __restrict__ Cout,
    int M, int N, int K, int GX)
{
    constexpr int WAVES = BLK / 64, WGM = WAVES / WGN;
    constexpr int MR = BM / (WGM * 16), NR = BN / (WGN * 16);
    constexpr int A_RND = BM * 8 / BLK, B_RND = BN * 8 / BLK;
    constexpr int LDS_HALF = (BM + BN) * 128;
    __shared__ __align__(16) char lds[2 * LDS_HALF];

    const int tid = threadIdx.x, lane = tid & 63, wid = tid >> 6;
    const int wm = wid / WGN, wn = wid % WGN;
    const int l15 = lane & 15, l4 = lane >> 4;
    const int cpx = gridDim.x >> 3;
    const int sbid = ((int)blockIdx.x & 7) * cpx + ((int)blockIdx.x >> 3);
    const int m0 = (sbid / GX) * BM, n0 = (sbid % GX) * BN;
    const int wu = tid & ~63;

    f32x4 acc[MR][NR] = {};
    const int NT = K >> 6;

    auto stage = [&](int b, int kt) {
        char* Ab = lds + b * LDS_HALF;
        char* Bb = Ab + BM * 128;
#pragma unroll
        for (int j = 0; j < A_RND; ++j) {
            int ch = j * BLK + tid, r = ch >> 3;
            int c = ((ch & 7) ^ (r & 7)) * 8;               // inverse-swizzled source
            gload_lds16(&A[(size_t)(m0 + r) * K + kt + c],
                        (bf16*)Ab + (size_t)(j * BLK + wu) * 8);
        }
#pragma unroll
        for (int j = 0; j < B_RND; ++j) {
            int ch = j * BLK + tid, r = ch >> 3;
            int c = ((ch & 7) ^ (r & 7)) * 8;
            gload_lds16(&Bt[(size_t)(n0 + r) * K + kt + c],
                        (bf16*)Bb + (size_t)(j * BLK + wu) * 8);
        }
    };

    stage(0, 0);
    asm volatile("s_waitcnt vmcnt(0)" ::: "memory");
    __builtin_amdgcn_s_barrier();

    for (int t = 0; t < NT; ++t) {
        if (t + 1 < NT) stage((t + 1) & 1, (t + 1) * 64);   // loads fly during compute
        const char* Ab = lds + (t & 1) * LDS_HALF;
        const char* Bb = Ab + BM * 128;
#pragma unroll
        for (int kk = 0; kk < 2; ++kk) {
            bf16x8 af[MR], bfr[NR];
#pragma unroll
            for (int mi = 0; mi < MR; ++mi) {
                int row = wm * (MR * 16) + mi * 16 + l15;
                af[mi] = *(const bf16x8*)(Ab + swz(row, kk * 64 + l4 * 16));
            }
#pragma unroll
            for (int ni = 0; ni < NR; ++ni) {
                int row = wn * (NR * 16) + ni * 16 + l15;
                bfr[ni] = *(const bf16x8*)(Bb + swz(row, kk * 64 + l4 * 16));
            }
#pragma unroll
            for (int mi = 0; mi < MR; ++mi)
#pragma unroll
                for (int ni = 0; ni < NR; ++ni)
                    acc[mi][ni] = __builtin_amdgcn_mfma_f32_16x16x32_bf16(
                        af[mi], bfr[ni], acc[mi][ni], 0, 0, 0);
        }
        asm volatile("s_waitcnt vmcnt(0)" ::: "memory");     // next tile landed
        __builtin_amdgcn_s_barrier();
    }

#pragma unroll
    for (int mi = 0; mi < MR; ++mi) {
#pragma unroll
        for (int ni = 0; ni < NR; ++ni) {
            int col = n0 + wn * (NR * 16) + ni * 16 + l15;
            float bv = bias[col];
#pragma unroll
            for (int r = 0; r < 4; ++r) {
                int row = m0 + wm * (MR * 16) + mi * 16 + l4 * 4 + r;
                float v = acc[mi][ni][r] + bv;
                if (OUT_BF16) ((bf16*)Cout)[(size_t)row * N + col] = (bf16)v;
                else          ((float*)Cout)[(size_t)row * N + col] = v;
            }
        }
    }
}

// ---------------- causal flash attention ----------------
// Block: 256 threads = 4 waves = 2 q-groups (32 rows) x 2 k-parities.
// Tile pair (2u, 2u+1) double-buffered in swizzled LDS; wave parity p computes
// tile 2u+p. End-of-block (m,l,O) merge across parities via LDS.
// Grid: 1024 blocks, longest-first (LPT) for dynamic balance.
__global__ __launch_bounds__(256, 3) void attn_kernel(
    const bf16* __restrict__ qkv, const bf16* __restrict__ Vt, bf16* __restrict__ attb)
{
    __shared__ __align__(16) char smem[32768];   // K bufs @0, V bufs @16384
    const int tid = threadIdx.x, lane = tid & 63, wid = tid >> 6;
    const int qg = wid >> 1, par = wid & 1;
    const int bid = blockIdx.x;
    const int iq = 31 - (bid >> 5);              // longest q-tiles dispatch first
    const int bh = bid & 31, b = bh >> 4, h = bh & 15;
    const int nt = iq + 1, npairs = (nt + 1) >> 1;
    const int l15 = lane & 15, l4 = lane >> 4;
    const size_t base = (size_t)b * T_SEQ * 3072;
    const int koff = 1024 + h * 64;
    const size_t vtb = (size_t)bh * 64 * T_SEQ;
    const int sr = tid >> 2, sq4 = tid & 3;      // staging: row, 32B-quarter

    const int q0 = iq * 64 + qg * 32;
    bf16x8 Qf[2][2];
#pragma unroll
    for (int qf = 0; qf < 2; ++qf)
#pragma unroll
        for (int dh = 0; dh < 2; ++dh)
            Qf[qf][dh] = *(const bf16x8*)&qkv[base + (size_t)(q0 + qf * 16 + l15) * 3072
                                             + h * 64 + dh * 32 + l4 * 8];

    f32x4 Oacc[4][2] = {};
    float m_run[2] = { -1e30f, -1e30f };
    float l_run[2] = { 0.f, 0.f };

    bf16x8 kreg[2][2], vreg[2][2];
    {   // prefetch pair 0
        const int pb = 0;
#pragma unroll
        for (int p = 0; p < 2; ++p)
#pragma unroll
            for (int j = 0; j < 2; ++j) {
                kreg[p][j] = *(const bf16x8*)&qkv[base + (size_t)(pb + p * 64 + sr) * 3072
                                                 + koff + sq4 * 16 + j * 8];
                vreg[p][j] = *(const bf16x8*)&Vt[vtb + (size_t)sr * T_SEQ + pb + p * 64 + sq4 * 16 + j * 8];
            }
    }

    for (int u = 0; u < npairs; ++u) {
        __syncthreads();                          // prev-tile reads done
#pragma unroll
        for (int p = 0; p < 2; ++p) {
            char* Kp = smem + p * 8192;
            char* Vp = smem + 16384 + p * 8192;
#pragma unroll
            for (int j = 0; j < 2; ++j) {
                const int byte = swz(sr, sq4 * 32 + j * 16);
                *(bf16x8*)(Kp + byte) = kreg[p][j];
                *(bf16x8*)(Vp + byte) = vreg[p][j];
            }
        }
        __syncthreads();                          // LDS ready
        if (u + 1 < npairs) {                     // prefetch next pair
            const int pb = (u + 1) * 128;
#pragma unroll
            for (int p = 0; p < 2; ++p)
#pragma unroll
                for (int j = 0; j < 2; ++j) {
                    kreg[p][j] = *(const bf16x8*)&qkv[base + (size_t)(pb + p * 64 + sr) * 3072
                                                     + koff + sq4 * 16 + j * 8];
                    vreg[p][j] = *(const bf16x8*)&Vt[vtb + (size_t)sr * T_SEQ + pb + p * 64 + sq4 * 16 + j * 8];
                }
        }
        const int t = 2 * u + par;
        if (t < nt) {
            const char* Kc = smem + par * 8192;
            const char* Vc = smem + 16384 + par * 8192;
            // S^T = K . Q  (raw, unscaled)
            f32x4 S[4][2] = {};
            __builtin_amdgcn_s_setprio(1);
#pragma unroll
            for (int dh = 0; dh < 2; ++dh)
#pragma unroll
                for (int kf = 0; kf < 4; ++kf) {
                    bf16x8 kfr = *(const bf16x8*)(Kc + swz(kf * 16 + l15, dh * 64 + l4 * 16));
#pragma unroll
                    for (int qf = 0; qf < 2; ++qf)
                        S[kf][qf] = __builtin_amdgcn_mfma_f32_16x16x32_bf16(
                            kfr, Qf[qf][dh], S[kf][qf], 0, 0, 0);
                }
            __builtin_amdgcn_s_setprio(0);
            const int diag = (t == nt - 1);
            s16x4 Pb[4][2];
#pragma unroll
            for (int qf = 0; qf < 2; ++qf) {
                float pmax = -3.0e38f;
                if (diag) {
                    const int qq = qg * 32 + qf * 16 + l15;    // tile-local q
#pragma unroll
                    for (int kf = 0; kf < 4; ++kf)
#pragma unroll
                        for (int r = 0; r < 4; ++r) {
                            if (kf * 16 + l4 * 4 + r > qq) S[kf][qf][r] = -3.0e38f;
                            pmax = fmaxf(pmax, S[kf][qf][r]);
                        }
                } else {
#pragma unroll
                    for (int kf = 0; kf < 4; ++kf)
#pragma unroll
                        for (int r = 0; r < 4; ++r) pmax = fmaxf(pmax, S[kf][qf][r]);
                }
                pmax = fmaxf(pmax, __shfl_xor(pmax, 16));
                pmax = fmaxf(pmax, __shfl_xor(pmax, 32));
                if (!__all(pmax - m_run[qf] <= 64.f)) {        // defer-rescale (8 in score dom.)
                    float mnew = fmaxf(m_run[qf], pmax);
                    float alpha = fast_exp2((m_run[qf] - mnew) * 0.18033688f);
                    m_run[qf] = mnew;
                    l_run[qf] *= alpha;
#pragma unroll
                    for (int df = 0; df < 4; ++df) Oacc[df][qf] *= alpha;
                }
                float lsum = 0.f;
#pragma unroll
                for (int kf = 0; kf < 4; ++kf)
#pragma unroll
                    for (int r = 0; r < 4; ++r) {
                        float p = fast_exp2((S[kf][qf][r] - m_run[qf]) * 0.18033688f);
                        lsum += p;
                        Pb[kf][qf][r] = __builtin_bit_cast(short, (bf16)p);
                    }
                lsum += __shfl_xor(lsum, 16);
                lsum += __shfl_xor(lsum, 32);
                l_run[qf] += lsum;
            }
            // out^T += V^T * P
            __builtin_amdgcn_s_setprio(1);
#pragma unroll
            for (int kf = 0; kf < 4; ++kf)
#pragma unroll
                for (int df = 0; df < 4; ++df) {
                    bf16x4 av = *(const bf16x4*)(Vc + swz(df * 16 + l15, kf * 32 + l4 * 8));
                    s16x4 avs = __builtin_bit_cast(s16x4, av);
#pragma unroll
                    for (int qf = 0; qf < 2; ++qf)
                        Oacc[df][qf] = __builtin_amdgcn_mfma_f32_16x16x16bf16_1k(
                            avs, Pb[kf][qf], Oacc[df][qf], 0, 0, 0);
                }
            __builtin_amdgcn_s_setprio(0);
        }
    }

    // ---- cross-parity merge (reuse LDS) ----
    float* cbuf = (float*)smem;                  // 128 lanes x 36 floats = 18KB
    __syncthreads();
    if (par == 1) {
        float* p = cbuf + (qg * 64 + lane) * 36;
#pragma unroll
        for (int df = 0; df < 4; ++df)
#pragma unroll
            for (int qf = 0; qf < 2; ++qf)
                *(f32x4*)(p + (df * 2 + qf) * 4) = Oacc[df][qf];
        p[32] = m_run[0]; p[33] = m_run[1]; p[34] = l_run[0]; p[35] = l_run[1];
    }
    __syncthreads();
    if (par == 0) {
        const float* p = cbuf + (qg * 64 + lane) * 36;
#pragma unroll
        for (int qf = 0; qf < 2; ++qf) {
            float m1 = p[32 + qf], l1 = p[34 + qf];
            float m = fmaxf(m_run[qf], m1);
            float a0 = fast_exp2((m_run[qf] - m) * 0.18033688f);
            float a1 = fast_exp2((m1 - m) * 0.18033688f);
            float inv = 1.f / (l_run[qf] * a0 + l1 * a1);
            const int qrow = q0 + qf * 16 + l15;
#pragma unroll
            for (int df = 0; df < 4; ++df) {
                const float* po = p + (df * 2 + qf) * 4;
                bf16x4 o;
#pragma unroll
                for (int r = 0; r < 4; ++r)
                    o[r] = (bf16)((Oacc[df][qf][r] * a0 + po[r] * a1) * inv);
                *(bf16x4*)&attb[((size_t)b * T_SEQ + qrow) * 1024 + h * 64 + df * 16 + l4 * 4] = o;
            }
        }
    }
}

// ---------------- launcher ----------------
extern "C" void kernel_launch(void* const* d_in, const int* in_sizes, int n_in,
                              void* d_out, int out_size, void* d_ws, size_t ws_size,
                              hipStream_t stream)
{
    const float* x    = (const float*)d_in[0];   // [2,2048,1024]
    const float* Wqkv = (const float*)d_in[1];   // [1024,3072]
    const float* bqkv = (const float*)d_in[2];   // [3072]
    const float* Wout = (const float*)d_in[3];   // [1024,1024]
    const float* bout = (const float*)d_in[4];   // [1024]
    float* out = (float*)d_out;                  // [2,2048,1024] f32

    char* ws = (char*)d_ws;
    bf16* xb    = (bf16*)(ws);                    // 8 MB (dead after gemm1)
    bf16* Vt    = (bf16*)(ws);                    // 8 MB, reuses xb region
    bf16* Wqkvt = (bf16*)(ws + (8ull  << 20));    // 6 MB
    bf16* Woutt = (bf16*)(ws + (14ull << 20));    // 2 MB
    bf16* qkvb  = (bf16*)(ws + (16ull << 20));    // 24 MB
    bf16* attb  = (bf16*)(ws + (40ull << 20));    // 8 MB

    convert_kernel<<<dim3(2048), dim3(256), 0, stream>>>(x, xb, (4096 * 1024) / 4);
    transpose_conv_kernel<<<dim3(96, 32), dim3(256), 0, stream>>>(Wqkv, Wqkvt, 1024, 3072);
    transpose_conv_kernel<<<dim3(32, 32), dim3(256), 0, stream>>>(Wout, Woutt, 1024, 1024);
    gemm2ph_kernel<256, 192, 512, 4, 1><<<dim3(256), dim3(512), 0, stream>>>(
        xb, Wqkvt, bqkv, (void*)qkvb, 4096, 3072, 1024, 16);
    vtrans_kernel<<<dim3(32, 32), dim3(256), 0, stream>>>(qkvb, Vt);
    attn_kernel<<<dim3(1024), dim3(256), 0, stream>>>(qkvb, Vt, attb);
    gemm2ph_kernel<128, 128, 256, 2, 0><<<dim3(256), dim3(256), 0, stream>>>(
        attb, Woutt, bout, (void*)out, 4096, 1024, 1024, 8);
}

// Round 7
// 101.503 us; speedup vs baseline: 1.4897x; 1.0352x over previous
//
#include <hip/hip_runtime.h>
#include <hip/hip_bf16.h>
#include <math.h>

typedef __bf16 bf16;
typedef __attribute__((ext_vector_type(8))) __bf16 bf16x8;
typedef __attribute__((ext_vector_type(4))) __bf16 bf16x4;
typedef __attribute__((ext_vector_type(4))) short s16x4;
typedef __attribute__((ext_vector_type(4))) float f32x4;
typedef __attribute__((ext_vector_type(16))) float f32x16;
typedef __attribute__((ext_vector_type(4))) unsigned u32x4;

#define T_SEQ 2048

static __device__ __forceinline__ float fast_exp2(float x) {
#if __has_builtin(__builtin_amdgcn_exp2f)
    return __builtin_amdgcn_exp2f(x);
#else
    return __expf(x * 0.69314718f);
#endif
}

// pack two floats to bf16x2 in a u32 (low = first)
static __device__ __forceinline__ unsigned pk(float lo, float hi) {
    unsigned a = (unsigned)__builtin_bit_cast(unsigned short, (bf16)lo);
    unsigned b = (unsigned)__builtin_bit_cast(unsigned short, (bf16)hi);
    return a | (b << 16);
}

// async global->LDS, 16B per lane (HW: wave-uniform LDS base + lane*16)
static __device__ __forceinline__ void gload_lds16(const bf16* g, bf16* l) {
    __builtin_amdgcn_global_load_lds((const __attribute__((address_space(1))) void*)g,
                                     (__attribute__((address_space(3))) void*)l, 16, 0, 0);
}

// XOR swizzle within a 128B row: spreads 8 rows across 8 16B bank-slots
static __device__ __forceinline__ int swz(int row, int colb) {
    return row * 128 + (colb ^ ((row & 7) << 4));
}

// ---------------- fp32 -> bf16 elementwise convert (x) ----------------
__global__ void convert_kernel(const float* __restrict__ x, bf16* __restrict__ xb, int n4)
{
    int i = blockIdx.x * blockDim.x + threadIdx.x;
    int stride = gridDim.x * blockDim.x;
    for (; i < n4; i += stride) {
        f32x4 v = ((const f32x4*)x)[i];
        bf16x4 o;
        o[0] = (bf16)v[0]; o[1] = (bf16)v[1]; o[2] = (bf16)v[2]; o[3] = (bf16)v[3];
        ((bf16x4*)xb)[i] = o;
    }
}

// ---------------- tiled transpose + convert: W[K][N] f32 -> Wt[N][K] bf16 ----------------
__global__ __launch_bounds__(256) void transpose_conv_kernel(
    const float* __restrict__ W, bf16* __restrict__ Wt, int K, int N)
{
    __shared__ float tile[32][33];
    int tx = threadIdx.x & 31, ty = threadIdx.x >> 5;       // ty 0..7
    int n0 = blockIdx.x * 32, k0 = blockIdx.y * 32;
#pragma unroll
    for (int j = 0; j < 4; ++j)
        tile[ty + j * 8][tx] = W[(size_t)(k0 + ty + j * 8) * N + n0 + tx];
    __syncthreads();
#pragma unroll
    for (int j = 0; j < 4; ++j)
        Wt[(size_t)(n0 + ty + j * 8) * K + k0 + tx] = (bf16)tile[tx][ty + j * 8];
}

// ---------------- V pre-transpose: Vt[bh][d][t] = qkv[b][t][2048 + h*64 + d] ----------------
__global__ __launch_bounds__(256) void vtrans_kernel(
    const bf16* __restrict__ qkv, bf16* __restrict__ Vt)
{
    __shared__ bf16 tile[64][72];
    const int tid = threadIdx.x;
    const int bh = blockIdx.y, b = bh >> 4, h = bh & 15;
    const int t0 = blockIdx.x * 64;
    const size_t base = (size_t)b * T_SEQ * 3072 + 2048 + h * 64;
    const int r = tid >> 3, c = (tid & 7) * 8;
    *(bf16x8*)&tile[r][c]      = *(const bf16x8*)&qkv[base + (size_t)(t0 + r) * 3072 + c];
    *(bf16x8*)&tile[r + 32][c] = *(const bf16x8*)&qkv[base + (size_t)(t0 + r + 32) * 3072 + c];
    __syncthreads();
    bf16x8 o0, o1;
#pragma unroll
    for (int j = 0; j < 8; ++j) { o0[j] = tile[c + j][r]; o1[j] = tile[c + j][r + 32]; }
    *(bf16x8*)&Vt[((size_t)bh * 64 + r) * T_SEQ + t0 + c] = o0;
    *(bf16x8*)&Vt[((size_t)bh * 64 + r + 32) * T_SEQ + t0 + c] = o1;
}

// ---------------- GEMM: C = A[M][K] * Bt[N][K]^T + bias ----------------
// Minimal-2-phase dbuf template: STAGE(next) -> COMPUTE(cur) -> vmcnt(0)+barrier.
template<int BM, int BN, int BLK, int WGN, int OUT_BF16>
__global__ __launch_bounds__(BLK, 2) void gemm2ph_kernel(
    const bf16* __restrict__ A, const bf16* __restrict__ Bt,
    const float* __restrict__ bias, void* __restrict__ Cout,
    int M, int N, int K, int GX)
{
    constexpr int WAVES = BLK / 64, WGM = WAVES / WGN;
    constexpr int MR = BM / (WGM * 16), NR = BN / (WGN * 16);
    constexpr int A_RND = BM * 8 / BLK, B_RND = BN * 8 / BLK;
    constexpr int LDS_HALF = (BM + BN) * 128;
    __shared__ __align__(16) char lds[2 * LDS_HALF];

    const int tid = threadIdx.x, lane = tid & 63, wid = tid >> 6;
    const int wm = wid / WGN, wn = wid % WGN;
    const int l15 = lane & 15, l4 = lane >> 4;
    const int cpx = gridDim.x >> 3;
    const int sbid = ((int)blockIdx.x & 7) * cpx + ((int)blockIdx.x >> 3);
    const int m0 = (sbid / GX) * BM, n0 = (sbid % GX) * BN;
    const int wu = tid & ~63;

    f32x4 acc[MR][NR] = {};
    const int NT = K >> 6;

    auto stage = [&](int b, int kt) {
        char* Ab = lds + b * LDS_HALF;
        char* Bb = Ab + BM * 128;
#pragma unroll
        for (int j = 0; j < A_RND; ++j) {
            int ch = j * BLK + tid, r = ch >> 3;
            int c = ((ch & 7) ^ (r & 7)) * 8;               // inverse-swizzled source
            gload_lds16(&A[(size_t)(m0 + r) * K + kt + c],
                        (bf16*)Ab + (size_t)(j * BLK + wu) * 8);
        }
#pragma unroll
        for (int j = 0; j < B_RND; ++j) {
            int ch = j * BLK + tid, r = ch >> 3;
            int c = ((ch & 7) ^ (r & 7)) * 8;
            gload_lds16(&Bt[(size_t)(n0 + r) * K + kt + c],
                        (bf16*)Bb + (size_t)(j * BLK + wu) * 8);
        }
    };

    stage(0, 0);
    asm volatile("s_waitcnt vmcnt(0)" ::: "memory");
    __builtin_amdgcn_s_barrier();

    for (int t = 0; t < NT; ++t) {
        if (t + 1 < NT) stage((t + 1) & 1, (t + 1) * 64);   // loads fly during compute
        const char* Ab = lds + (t & 1) * LDS_HALF;
        const char* Bb = Ab + BM * 128;
#pragma unroll
        for (int kk = 0; kk < 2; ++kk) {
            bf16x8 af[MR], bfr[NR];
#pragma unroll
            for (int mi = 0; mi < MR; ++mi) {
                int row = wm * (MR * 16) + mi * 16 + l15;
                af[mi] = *(const bf16x8*)(Ab + swz(row, kk * 64 + l4 * 16));
            }
#pragma unroll
            for (int ni = 0; ni < NR; ++ni) {
                int row = wn * (NR * 16) + ni * 16 + l15;
                bfr[ni] = *(const bf16x8*)(Bb + swz(row, kk * 64 + l4 * 16));
            }
#pragma unroll
            for (int mi = 0; mi < MR; ++mi)
#pragma unroll
                for (int ni = 0; ni < NR; ++ni)
                    acc[mi][ni] = __builtin_amdgcn_mfma_f32_16x16x32_bf16(
                        af[mi], bfr[ni], acc[mi][ni], 0, 0, 0);
        }
        asm volatile("s_waitcnt vmcnt(0)" ::: "memory");     // next tile landed
        __builtin_amdgcn_s_barrier();
    }

#pragma unroll
    for (int mi = 0; mi < MR; ++mi) {
#pragma unroll
        for (int ni = 0; ni < NR; ++ni) {
            int col = n0 + wn * (NR * 16) + ni * 16 + l15;
            float bv = bias[col];
#pragma unroll
            for (int r = 0; r < 4; ++r) {
                int row = m0 + wm * (MR * 16) + mi * 16 + l4 * 4 + r;
                float v = acc[mi][ni][r] + bv;
                if (OUT_BF16) ((bf16*)Cout)[(size_t)row * N + col] = (bf16)v;
                else          ((float*)Cout)[(size_t)row * N + col] = v;
            }
        }
    }
}

// ---------------- causal flash attention (32x32 MFMA core) ----------------
// Block: 256 threads = 4 waves = 2 q-groups (32 rows) x 2 k-parities.
// Per wave-tile: QK^T = 8x mfma_32x32x16 (S^T, two 32k C-tiles), softmax in-reg
// (q = lane&31), P relayout via cvt_pk + permlane32_swap in GUIDE order
// (swap(P01,P45): r[0]=wv[0], r[1]=wv[2]), PV = 8x mfma_32x32x16 (full rate).
__global__ __launch_bounds__(256, 3) void attn_kernel(
    const bf16* __restrict__ qkv, const bf16* __restrict__ Vt, bf16* __restrict__ attb)
{
    __shared__ __align__(16) char smem[32768];   // K bufs @0, V bufs @16384
    const int tid = threadIdx.x, lane = tid & 63, wid = tid >> 6;
    const int qg = wid >> 1, par = wid & 1;
    const int bid = blockIdx.x;
    const int iq = 31 - (bid >> 5);              // longest q-tiles dispatch first
    const int bh = bid & 31, b = bh >> 4, h = bh & 15;
    const int nt = iq + 1, npairs = (nt + 1) >> 1;
    const int l31 = lane & 31, hi = lane >> 5, hib = hi * 16;
    const size_t base = (size_t)b * T_SEQ * 3072;
    const int koff = 1024 + h * 64;
    const size_t vtb = (size_t)bh * 64 * T_SEQ;
    const int sr = tid >> 2, sq4 = tid & 3;      // staging: row, 32B-quarter

    const int q0 = iq * 64 + qg * 32;
    const int qrow = q0 + l31;

    // Q fragments: B-operand of 32x32x16, d = ds*16 + hi*8 + i
    bf16x8 Qf[4];
#pragma unroll
    for (int ds = 0; ds < 4; ++ds)
        Qf[ds] = *(const bf16x8*)&qkv[base + (size_t)qrow * 3072 + h * 64 + ds * 16 + hi * 8];

    f32x16 Oacc[2] = {};
    float m_run = -1e30f, l_run = 0.f;

    bf16x8 kreg[2][2], vreg[2][2];
    {   // prefetch pair 0
#pragma unroll
        for (int p = 0; p < 2; ++p)
#pragma unroll
            for (int j = 0; j < 2; ++j) {
                kreg[p][j] = *(const bf16x8*)&qkv[base + (size_t)(p * 64 + sr) * 3072
                                                 + koff + sq4 * 16 + j * 8];
                vreg[p][j] = *(const bf16x8*)&Vt[vtb + (size_t)sr * T_SEQ + p * 64 + sq4 * 16 + j * 8];
            }
    }

    for (int u = 0; u < npairs; ++u) {
        __syncthreads();                          // prev-tile reads done
#pragma unroll
        for (int p = 0; p < 2; ++p) {
            char* Kp = smem + p * 8192;
            char* Vp = smem + 16384 + p * 8192;
#pragma unroll
            for (int j = 0; j < 2; ++j) {
                const int byte = swz(sr, sq4 * 32 + j * 16);
                *(bf16x8*)(Kp + byte) = kreg[p][j];
                *(bf16x8*)(Vp + byte) = vreg[p][j];
            }
        }
        __syncthreads();                          // LDS ready
        if (u + 1 < npairs) {                     // prefetch next pair
            const int pb = (u + 1) * 128;
#pragma unroll
            for (int p = 0; p < 2; ++p)
#pragma unroll
                for (int j = 0; j < 2; ++j) {
                    kreg[p][j] = *(const bf16x8*)&qkv[base + (size_t)(pb + p * 64 + sr) * 3072
                                                     + koff + sq4 * 16 + j * 8];
                    vreg[p][j] = *(const bf16x8*)&Vt[vtb + (size_t)sr * T_SEQ + pb + p * 64 + sq4 * 16 + j * 8];
                }
        }
        const int t = 2 * u + par;
        if (t < nt) {
            const char* Kc = smem + par * 8192;
            const char* Vc = smem + 16384 + par * 8192;
            // ---- S^T = K . Q : two 32x32 C-tiles (k-halves), contraction d=64 ----
            f32x16 S[2] = {};
            __builtin_amdgcn_s_setprio(1);
#pragma unroll
            for (int ds = 0; ds < 4; ++ds)
#pragma unroll
                for (int kt = 0; kt < 2; ++kt) {
                    bf16x8 af = *(const bf16x8*)(Kc + swz(kt * 32 + l31, ds * 32 + hib));
                    S[kt] = __builtin_amdgcn_mfma_f32_32x32x16_bf16(af, Qf[ds], S[kt], 0, 0, 0);
                }
            __builtin_amdgcn_s_setprio(0);
            // ---- mask (diag only) + row max (k spans lane-halves) ----
            float pmax = -3.0e38f;
            if (t == nt - 1) {
                const int qloc = qg * 32 + l31;
#pragma unroll
                for (int kt = 0; kt < 2; ++kt)
#pragma unroll
                    for (int j = 0; j < 16; ++j) {
                        const int kloc = kt * 32 + (j & 3) + 8 * (j >> 2) + 4 * hi;
                        if (kloc > qloc) S[kt][j] = -3.0e38f;
                        pmax = fmaxf(pmax, S[kt][j]);
                    }
            } else {
#pragma unroll
                for (int kt = 0; kt < 2; ++kt)
#pragma unroll
                    for (int j = 0; j < 16; ++j) pmax = fmaxf(pmax, S[kt][j]);
            }
            pmax = fmaxf(pmax, __shfl_xor(pmax, 32));
            // ---- defer-rescale (raw-domain threshold 64 == 8 in score domain) ----
            if (!__all(pmax - m_run <= 64.f)) {
                float mnew = fmaxf(m_run, pmax);
                float alpha = fast_exp2((m_run - mnew) * 0.18033688f);
                m_run = mnew;
                l_run *= alpha;
                Oacc[0] *= alpha;
                Oacc[1] *= alpha;
            }
            // ---- P = exp2((S-m)*c), in place; row sum ----
            float lsum = 0.f;
#pragma unroll
            for (int kt = 0; kt < 2; ++kt)
#pragma unroll
                for (int j = 0; j < 16; ++j) {
                    float p = fast_exp2((S[kt][j] - m_run) * 0.18033688f);
                    S[kt][j] = p;
                    lsum += p;
                }
            lsum += __shfl_xor(lsum, 32);
            l_run += lsum;
            // ---- pack P to 32x32x16 B-operand: guide-order permlane32_swap ----
            __builtin_amdgcn_s_setprio(1);
#pragma unroll
            for (int ks = 0; ks < 4; ++ks) {
                const int kt = ks >> 1, bs = (ks & 1) * 8;
                unsigned P01 = pk(S[kt][bs + 0], S[kt][bs + 1]);
                unsigned P23 = pk(S[kt][bs + 2], S[kt][bs + 3]);
                unsigned P45 = pk(S[kt][bs + 4], S[kt][bs + 5]);
                unsigned P67 = pk(S[kt][bs + 6], S[kt][bs + 7]);
                auto r02 = __builtin_amdgcn_permlane32_swap(P01, P45, false, false);
                auto r13 = __builtin_amdgcn_permlane32_swap(P23, P67, false, false);
                u32x4 wv;
                wv[0] = r02[0]; wv[1] = r13[0]; wv[2] = r02[1]; wv[3] = r13[1];
                bf16x8 Bfrag = __builtin_bit_cast(bf16x8, wv);
#pragma unroll
                for (int dt = 0; dt < 2; ++dt) {
                    bf16x8 av = *(const bf16x8*)(Vc + swz(dt * 32 + l31, ks * 32 + hib));
                    Oacc[dt] = __builtin_amdgcn_mfma_f32_32x32x16_bf16(av, Bfrag, Oacc[dt], 0, 0, 0);
                }
            }
            __builtin_amdgcn_s_setprio(0);
        }
    }

    // ---- cross-parity merge (reuse LDS) ----
    float* cbuf = (float*)smem;                  // 128 lanes x 36 floats = 18KB
    __syncthreads();
    if (par == 1) {
        float* p = cbuf + (qg * 64 + lane) * 36;
#pragma unroll
        for (int dt = 0; dt < 2; ++dt)
#pragma unroll
            for (int j = 0; j < 16; ++j) p[dt * 16 + j] = Oacc[dt][j];
        p[32] = m_run; p[33] = l_run;
    }
    __syncthreads();
    if (par == 0) {
        const float* p = cbuf + (qg * 64 + lane) * 36;
        float m1 = p[32], l1 = p[33];
        float m = fmaxf(m_run, m1);
        float a0 = fast_exp2((m_run - m) * 0.18033688f);
        float a1 = fast_exp2((m1 - m) * 0.18033688f);
        float inv = 1.f / (l_run * a0 + l1 * a1);
#pragma unroll
        for (int dt = 0; dt < 2; ++dt) {
#pragma unroll
            for (int g = 0; g < 4; ++g) {
                bf16x4 o;
#pragma unroll
                for (int j = 0; j < 4; ++j)
                    o[j] = (bf16)((Oacc[dt][g * 4 + j] * a0 + p[dt * 16 + g * 4 + j] * a1) * inv);
                const int d = dt * 32 + g * 8 + 4 * hi;
                *(bf16x4*)&attb[((size_t)b * T_SEQ + qrow) * 1024 + h * 64 + d] = o;
            }
        }
    }
}

// ---------------- launcher ----------------
extern "C" void kernel_launch(void* const* d_in, const int* in_sizes, int n_in,
                              void* d_out, int out_size, void* d_ws, size_t ws_size,
                              hipStream_t stream)
{
    const float* x    = (const float*)d_in[0];   // [2,2048,1024]
    const float* Wqkv = (const float*)d_in[1];   // [1024,3072]
    const float* bqkv = (const float*)d_in[2];   // [3072]
    const float* Wout = (const float*)d_in[3];   // [1024,1024]
    const float* bout = (const float*)d_in[4];   // [1024]
    float* out = (float*)d_out;                  // [2,2048,1024] f32

    char* ws = (char*)d_ws;
    bf16* xb    = (bf16*)(ws);                    // 8 MB (dead after gemm1)
    bf16* Vt    = (bf16*)(ws);                    // 8 MB, reuses xb region
    bf16* Wqkvt = (bf16*)(ws + (8ull  << 20));    // 6 MB
    bf16* Woutt = (bf16*)(ws + (14ull << 20));    // 2 MB
    bf16* qkvb  = (bf16*)(ws + (16ull << 20));    // 24 MB
    bf16* attb  = (bf16*)(ws + (40ull << 20));    // 8 MB

    convert_kernel<<<dim3(2048), dim3(256), 0, stream>>>(x, xb, (4096 * 1024) / 4);
    transpose_conv_kernel<<<dim3(96, 32), dim3(256), 0, stream>>>(Wqkv, Wqkvt, 1024, 3072);
    transpose_conv_kernel<<<dim3(32, 32), dim3(256), 0, stream>>>(Wout, Woutt, 1024, 1024);
    gemm2ph_kernel<256, 192, 512, 4, 1><<<dim3(256), dim3(512), 0, stream>>>(
        xb, Wqkvt, bqkv, (void*)qkvb, 4096, 3072, 1024, 16);
    vtrans_kernel<<<dim3(32, 32), dim3(256), 0, stream>>>(qkvb, Vt);
    attn_kernel<<<dim3(1024), dim3(256), 0, stream>>>(qkvb, Vt, attb);
    gemm2ph_kernel<128, 128, 256, 2, 0><<<dim3(256), dim3(256), 0, stream>>>(
        attb, Woutt, bout, (void*)out, 4096, 1024, 1024, 8);
}

// Round 8
// 100.020 us; speedup vs baseline: 1.5118x; 1.0148x over previous
//
#include <hip/hip_runtime.h>
#include <hip/hip_bf16.h>
#include <math.h>

typedef __bf16 bf16;
typedef __attribute__((ext_vector_type(8))) __bf16 bf16x8;
typedef __attribute__((ext_vector_type(4))) __bf16 bf16x4;
typedef __attribute__((ext_vector_type(4))) float f32x4;
typedef __attribute__((ext_vector_type(16))) float f32x16;
typedef __attribute__((ext_vector_type(4))) unsigned u32x4;

#define T_SEQ 2048

static __device__ __forceinline__ float fast_exp2(float x) {
#if __has_builtin(__builtin_amdgcn_exp2f)
    return __builtin_amdgcn_exp2f(x);
#else
    return __expf(x * 0.69314718f);
#endif
}

// pack two floats to bf16x2 in a u32 (low = first)
static __device__ __forceinline__ unsigned pk(float lo, float hi) {
    unsigned a = (unsigned)__builtin_bit_cast(unsigned short, (bf16)lo);
    unsigned b = (unsigned)__builtin_bit_cast(unsigned short, (bf16)hi);
    return a | (b << 16);
}

// async global->LDS, 16B per lane (HW: wave-uniform LDS base + lane*16)
static __device__ __forceinline__ void gload_lds16(const bf16* g, bf16* l) {
    __builtin_amdgcn_global_load_lds((const __attribute__((address_space(1))) void*)g,
                                     (__attribute__((address_space(3))) void*)l, 16, 0, 0);
}

// XOR swizzle within a 128B row: spreads 8 rows across 8 16B bank-slots
static __device__ __forceinline__ int swz(int row, int colb) {
    return row * 128 + (colb ^ ((row & 7) << 4));
}

// ---------------- fp32 -> bf16 elementwise convert (x) ----------------
__global__ void convert_kernel(const float* __restrict__ x, bf16* __restrict__ xb, int n4)
{
    int i = blockIdx.x * blockDim.x + threadIdx.x;
    int stride = gridDim.x * blockDim.x;
    for (; i < n4; i += stride) {
        f32x4 v = ((const f32x4*)x)[i];
        bf16x4 o;
        o[0] = (bf16)v[0]; o[1] = (bf16)v[1]; o[2] = (bf16)v[2]; o[3] = (bf16)v[3];
        ((bf16x4*)xb)[i] = o;
    }
}

// ---------------- tiled transpose + convert: W[K][N] f32 -> Wt[N][K] bf16 ----------------
__global__ __launch_bounds__(256) void transpose_conv_kernel(
    const float* __restrict__ W, bf16* __restrict__ Wt, int K, int N)
{
    __shared__ float tile[32][33];
    int tx = threadIdx.x & 31, ty = threadIdx.x >> 5;       // ty 0..7
    int n0 = blockIdx.x * 32, k0 = blockIdx.y * 32;
#pragma unroll
    for (int j = 0; j < 4; ++j)
        tile[ty + j * 8][tx] = W[(size_t)(k0 + ty + j * 8) * N + n0 + tx];
    __syncthreads();
#pragma unroll
    for (int j = 0; j < 4; ++j)
        Wt[(size_t)(n0 + ty + j * 8) * K + k0 + tx] = (bf16)tile[tx][ty + j * 8];
}

// ---------------- V pre-transpose: Vt[bh][d][t] = qkv[b][t][2048 + h*64 + d] ----------------
__global__ __launch_bounds__(256) void vtrans_kernel(
    const bf16* __restrict__ qkv, bf16* __restrict__ Vt)
{
    __shared__ bf16 tile[64][72];
    const int tid = threadIdx.x;
    const int bh = blockIdx.y, b = bh >> 4, h = bh & 15;
    const int t0 = blockIdx.x * 64;
    const size_t base = (size_t)b * T_SEQ * 3072 + 2048 + h * 64;
    const int r = tid >> 3, c = (tid & 7) * 8;
    *(bf16x8*)&tile[r][c]      = *(const bf16x8*)&qkv[base + (size_t)(t0 + r) * 3072 + c];
    *(bf16x8*)&tile[r + 32][c] = *(const bf16x8*)&qkv[base + (size_t)(t0 + r + 32) * 3072 + c];
    __syncthreads();
    bf16x8 o0, o1;
#pragma unroll
    for (int j = 0; j < 8; ++j) { o0[j] = tile[c + j][r]; o1[j] = tile[c + j][r + 32]; }
    *(bf16x8*)&Vt[((size_t)bh * 64 + r) * T_SEQ + t0 + c] = o0;
    *(bf16x8*)&Vt[((size_t)bh * 64 + r + 32) * T_SEQ + t0 + c] = o1;
}

// ---------------- GEMM: C = A[M][K] * Bt[N][K]^T + bias ----------------
// Minimal-2-phase dbuf template: STAGE(next) -> COMPUTE(cur) -> vmcnt(0)+barrier.
// LDS sized for >=2 blocks/CU so cross-block wave overlap hides the drain.
template<int BM, int BN, int BLK, int WGN, int OUT_BF16>
__global__ __launch_bounds__(BLK, 2) void gemm2ph_kernel(
    const bf16* __restrict__ A, const bf16* __restrict__ Bt,
    const float* __restrict__ bias, void* __restrict__ Cout,
    int M, int N, int K, int GX)
{
    constexpr int WAVES = BLK / 64, WGM = WAVES / WGN;
    constexpr int MR = BM / (WGM * 16), NR = BN / (WGN * 16);
    constexpr int A_RND = BM * 8 / BLK, B_RND = BN * 8 / BLK;
    constexpr int LDS_HALF = (BM + BN) * 128;
    __shared__ __align__(16) char lds[2 * LDS_HALF];

    const int tid = threadIdx.x, lane = tid & 63, wid = tid >> 6;
    const int wm = wid / WGN, wn = wid % WGN;
    const int l15 = lane & 15, l4 = lane >> 4;
    const int cpx = gridDim.x >> 3;
    const int sbid = ((int)blockIdx.x & 7) * cpx + ((int)blockIdx.x >> 3);
    const int m0 = (sbid / GX) * BM, n0 = (sbid % GX) * BN;
    const int wu = tid & ~63;

    f32x4 acc[MR][NR] = {};
    const int NT = K >> 6;

    auto stage = [&](int b, int kt) {
        char* Ab = lds + b * LDS_HALF;
        char* Bb = Ab + BM * 128;
#pragma unroll
        for (int j = 0; j < A_RND; ++j) {
            int ch = j * BLK + tid, r = ch >> 3;
            int c = ((ch & 7) ^ (r & 7)) * 8;               // inverse-swizzled source
            gload_lds16(&A[(size_t)(m0 + r) * K + kt + c],
                        (bf16*)Ab + (size_t)(j * BLK + wu) * 8);
        }
#pragma unroll
        for (int j = 0; j < B_RND; ++j) {
            int ch = j * BLK + tid, r = ch >> 3;
            int c = ((ch & 7) ^ (r & 7)) * 8;
            gload_lds16(&Bt[(size_t)(n0 + r) * K + kt + c],
                        (bf16*)Bb + (size_t)(j * BLK + wu) * 8);
        }
    };

    stage(0, 0);
    asm volatile("s_waitcnt vmcnt(0)" ::: "memory");
    __builtin_amdgcn_s_barrier();

    for (int t = 0; t < NT; ++t) {
        if (t + 1 < NT) stage((t + 1) & 1, (t + 1) * 64);   // loads fly during compute
        const char* Ab = lds + (t & 1) * LDS_HALF;
        const char* Bb = Ab + BM * 128;
#pragma unroll
        for (int kk = 0; kk < 2; ++kk) {
            bf16x8 af[MR], bfr[NR];
#pragma unroll
            for (int mi = 0; mi < MR; ++mi) {
                int row = wm * (MR * 16) + mi * 16 + l15;
                af[mi] = *(const bf16x8*)(Ab + swz(row, kk * 64 + l4 * 16));
            }
#pragma unroll
            for (int ni = 0; ni < NR; ++ni) {
                int row = wn * (NR * 16) + ni * 16 + l15;
                bfr[ni] = *(const bf16x8*)(Bb + swz(row, kk * 64 + l4 * 16));
            }
#pragma unroll
            for (int mi = 0; mi < MR; ++mi)
#pragma unroll
                for (int ni = 0; ni < NR; ++ni)
                    acc[mi][ni] = __builtin_amdgcn_mfma_f32_16x16x32_bf16(
                        af[mi], bfr[ni], acc[mi][ni], 0, 0, 0);
        }
        asm volatile("s_waitcnt vmcnt(0)" ::: "memory");     // next tile landed
        __builtin_amdgcn_s_barrier();
    }

#pragma unroll
    for (int mi = 0; mi < MR; ++mi) {
#pragma unroll
        for (int ni = 0; ni < NR; ++ni) {
            int col = n0 + wn * (NR * 16) + ni * 16 + l15;
            float bv = bias[col];
#pragma unroll
            for (int r = 0; r < 4; ++r) {
                int row = m0 + wm * (MR * 16) + mi * 16 + l4 * 4 + r;
                float v = acc[mi][ni][r] + bv;
                if (OUT_BF16) ((bf16*)Cout)[(size_t)row * N + col] = (bf16)v;
                else          ((float*)Cout)[(size_t)row * N + col] = v;
            }
        }
    }
}

// ---------------- causal flash attention (32x32 MFMA core) ----------------
// Block: 256 threads = 4 waves = 2 q-groups (32 rows) x 2 k-parities.
// QK^T = 8x mfma_32x32x16; softmax in-reg (q = lane&31); P relayout via
// cvt_pk + permlane32_swap; PV = 8x mfma_32x32x16; row-sum l via ones-MFMA
// (lacc = mfma(ones, P) -- moves 32 VALU adds/tile to the matrix pipe).
__global__ __launch_bounds__(256, 3) void attn_kernel(
    const bf16* __restrict__ qkv, const bf16* __restrict__ Vt, bf16* __restrict__ attb)
{
    __shared__ __align__(16) char smem[32768];   // K bufs @0, V bufs @16384
    const int tid = threadIdx.x, lane = tid & 63, wid = tid >> 6;
    const int qg = wid >> 1, par = wid & 1;
    const int bid = blockIdx.x;
    const int iq = 31 - (bid >> 5);              // longest q-tiles dispatch first
    const int bh = bid & 31, b = bh >> 4, h = bh & 15;
    const int nt = iq + 1, npairs = (nt + 1) >> 1;
    const int l31 = lane & 31, hi = lane >> 5, hib = hi * 16;
    const size_t base = (size_t)b * T_SEQ * 3072;
    const int koff = 1024 + h * 64;
    const size_t vtb = (size_t)bh * 64 * T_SEQ;
    const int sr = tid >> 2, sq4 = tid & 3;      // staging: row, 32B-quarter

    const int q0 = iq * 64 + qg * 32;
    const int qrow = q0 + l31;

    // Q fragments: B-operand of 32x32x16, d = ds*16 + hi*8 + i
    bf16x8 Qf[4];
#pragma unroll
    for (int ds = 0; ds < 4; ++ds)
        Qf[ds] = *(const bf16x8*)&qkv[base + (size_t)qrow * 3072 + h * 64 + ds * 16 + hi * 8];

    bf16x8 onesA;
#pragma unroll
    for (int j = 0; j < 8; ++j) onesA[j] = (bf16)1.0f;

    f32x16 Oacc[2] = {};
    f32x16 lacc = {};                            // all 16 elements == running l[q]
    float m_run = -1e30f;

    bf16x8 kreg[2][2], vreg[2][2];
    {   // prefetch pair 0
#pragma unroll
        for (int p = 0; p < 2; ++p)
#pragma unroll
            for (int j = 0; j < 2; ++j) {
                kreg[p][j] = *(const bf16x8*)&qkv[base + (size_t)(p * 64 + sr) * 3072
                                                 + koff + sq4 * 16 + j * 8];
                vreg[p][j] = *(const bf16x8*)&Vt[vtb + (size_t)sr * T_SEQ + p * 64 + sq4 * 16 + j * 8];
            }
    }

    for (int u = 0; u < npairs; ++u) {
        __syncthreads();                          // prev-tile reads done
#pragma unroll
        for (int p = 0; p < 2; ++p) {
            char* Kp = smem + p * 8192;
            char* Vp = smem + 16384 + p * 8192;
#pragma unroll
            for (int j = 0; j < 2; ++j) {
                const int byte = swz(sr, sq4 * 32 + j * 16);
                *(bf16x8*)(Kp + byte) = kreg[p][j];
                *(bf16x8*)(Vp + byte) = vreg[p][j];
            }
        }
        __syncthreads();                          // LDS ready
        if (u + 1 < npairs) {                     // prefetch next pair
            const int pb = (u + 1) * 128;
#pragma unroll
            for (int p = 0; p < 2; ++p)
#pragma unroll
                for (int j = 0; j < 2; ++j) {
                    kreg[p][j] = *(const bf16x8*)&qkv[base + (size_t)(pb + p * 64 + sr) * 3072
                                                     + koff + sq4 * 16 + j * 8];
                    vreg[p][j] = *(const bf16x8*)&Vt[vtb + (size_t)sr * T_SEQ + pb + p * 64 + sq4 * 16 + j * 8];
                }
        }
        const int t = 2 * u + par;
        if (t < nt) {
            const char* Kc = smem + par * 8192;
            const char* Vc = smem + 16384 + par * 8192;
            // ---- S^T = K . Q : two 32x32 C-tiles (k-halves), contraction d=64 ----
            f32x16 S[2] = {};
            __builtin_amdgcn_s_setprio(1);
#pragma unroll
            for (int ds = 0; ds < 4; ++ds)
#pragma unroll
                for (int kt = 0; kt < 2; ++kt) {
                    bf16x8 af = *(const bf16x8*)(Kc + swz(kt * 32 + l31, ds * 32 + hib));
                    S[kt] = __builtin_amdgcn_mfma_f32_32x32x16_bf16(af, Qf[ds], S[kt], 0, 0, 0);
                }
            __builtin_amdgcn_s_setprio(0);
            // ---- causal mask (diagonal tile only, uniform branch) ----
            if (t == nt - 1) {
                const int qloc = qg * 32 + l31;
#pragma unroll
                for (int kt = 0; kt < 2; ++kt)
#pragma unroll
                    for (int j = 0; j < 16; ++j) {
                        const int kloc = kt * 32 + (j & 3) + 8 * (j >> 2) + 4 * hi;
                        if (kloc > qloc) S[kt][j] = -3.0e38f;
                    }
            }
            // ---- row max (pairs -> v_max3-fusable) ----
            float pmax = -3.0e38f;
#pragma unroll
            for (int kt = 0; kt < 2; ++kt)
#pragma unroll
                for (int j = 0; j < 16; j += 2)
                    pmax = fmaxf(fmaxf(S[kt][j], S[kt][j + 1]), pmax);
            pmax = fmaxf(pmax, __shfl_xor(pmax, 32));
            // ---- defer-rescale (raw-domain threshold 64 == 8 in score domain) ----
            if (!__all(pmax - m_run <= 64.f)) {
                float mnew = fmaxf(m_run, pmax);
                float alpha = fast_exp2((m_run - mnew) * 0.18033688f);
                m_run = mnew;
                Oacc[0] *= alpha;
                Oacc[1] *= alpha;
                lacc *= alpha;
            }
            // ---- P = exp2(S*c - m*c), in place ----
            const float mc = m_run * 0.18033688f;
#pragma unroll
            for (int kt = 0; kt < 2; ++kt)
#pragma unroll
                for (int j = 0; j < 16; ++j)
                    S[kt][j] = fast_exp2(__builtin_fmaf(S[kt][j], 0.18033688f, -mc));
            // ---- pack P to 32x32x16 B-operand + PV + ones-MFMA row-sum ----
            __builtin_amdgcn_s_setprio(1);
#pragma unroll
            for (int ks = 0; ks < 4; ++ks) {
                const int kt = ks >> 1, bs = (ks & 1) * 8;
                unsigned P01 = pk(S[kt][bs + 0], S[kt][bs + 1]);
                unsigned P23 = pk(S[kt][bs + 2], S[kt][bs + 3]);
                unsigned P45 = pk(S[kt][bs + 4], S[kt][bs + 5]);
                unsigned P67 = pk(S[kt][bs + 6], S[kt][bs + 7]);
                auto r02 = __builtin_amdgcn_permlane32_swap(P01, P45, false, false);
                auto r13 = __builtin_amdgcn_permlane32_swap(P23, P67, false, false);
                u32x4 wv;
                wv[0] = r02[0]; wv[1] = r13[0]; wv[2] = r02[1]; wv[3] = r13[1];
                bf16x8 Bfrag = __builtin_bit_cast(bf16x8, wv);
#pragma unroll
                for (int dt = 0; dt < 2; ++dt) {
                    bf16x8 av = *(const bf16x8*)(Vc + swz(dt * 32 + l31, ks * 32 + hib));
                    Oacc[dt] = __builtin_amdgcn_mfma_f32_32x32x16_bf16(av, Bfrag, Oacc[dt], 0, 0, 0);
                }
                lacc = __builtin_amdgcn_mfma_f32_32x32x16_bf16(onesA, Bfrag, lacc, 0, 0, 0);
            }
            __builtin_amdgcn_s_setprio(0);
        }
    }

    // ---- cross-parity merge (reuse LDS) ----
    float* cbuf = (float*)smem;                  // 128 lanes x 36 floats = 18KB
    __syncthreads();
    if (par == 1) {
        float* p = cbuf + (qg * 64 + lane) * 36;
#pragma unroll
        for (int dt = 0; dt < 2; ++dt)
#pragma unroll
            for (int j = 0; j < 16; ++j) p[dt * 16 + j] = Oacc[dt][j];
        p[32] = m_run; p[33] = lacc[0];
    }
    __syncthreads();
    if (par == 0) {
        const float* p = cbuf + (qg * 64 + lane) * 36;
        float m1 = p[32], l1 = p[33];
        float m = fmaxf(m_run, m1);
        float a0 = fast_exp2((m_run - m) * 0.18033688f);
        float a1 = fast_exp2((m1 - m) * 0.18033688f);
        float inv = 1.f / (lacc[0] * a0 + l1 * a1);
#pragma unroll
        for (int dt = 0; dt < 2; ++dt) {
#pragma unroll
            for (int g = 0; g < 4; ++g) {
                bf16x4 o;
#pragma unroll
                for (int j = 0; j < 4; ++j)
                    o[j] = (bf16)((Oacc[dt][g * 4 + j] * a0 + p[dt * 16 + g * 4 + j] * a1) * inv);
                const int d = dt * 32 + g * 8 + 4 * hi;
                *(bf16x4*)&attb[((size_t)b * T_SEQ + qrow) * 1024 + h * 64 + d] = o;
            }
        }
    }
}

// ---------------- launcher ----------------
extern "C" void kernel_launch(void* const* d_in, const int* in_sizes, int n_in,
                              void* d_out, int out_size, void* d_ws, size_t ws_size,
                              hipStream_t stream)
{
    const float* x    = (const float*)d_in[0];   // [2,2048,1024]
    const float* Wqkv = (const float*)d_in[1];   // [1024,3072]
    const float* bqkv = (const float*)d_in[2];   // [3072]
    const float* Wout = (const float*)d_in[3];   // [1024,1024]
    const float* bout = (const float*)d_in[4];   // [1024]
    float* out = (float*)d_out;                  // [2,2048,1024] f32

    char* ws = (char*)d_ws;
    bf16* xb    = (bf16*)(ws);                    // 8 MB (dead after gemm1)
    bf16* Vt    = (bf16*)(ws);                    // 8 MB, reuses xb region
    bf16* Wqkvt = (bf16*)(ws + (8ull  << 20));    // 6 MB
    bf16* Woutt = (bf16*)(ws + (14ull << 20));    // 2 MB
    bf16* qkvb  = (bf16*)(ws + (16ull << 20));    // 24 MB
    bf16* attb  = (bf16*)(ws + (40ull << 20));    // 8 MB

    convert_kernel<<<dim3(2048), dim3(256), 0, stream>>>(x, xb, (4096 * 1024) / 4);
    transpose_conv_kernel<<<dim3(96, 32), dim3(256), 0, stream>>>(Wqkv, Wqkvt, 1024, 3072);
    transpose_conv_kernel<<<dim3(32, 32), dim3(256), 0, stream>>>(Wout, Woutt, 1024, 1024);
    gemm2ph_kernel<128, 192, 256, 2, 1><<<dim3(512), dim3(256), 0, stream>>>(
        xb, Wqkvt, bqkv, (void*)qkvb, 4096, 3072, 1024, 16);
    vtrans_kernel<<<dim3(32, 32), dim3(256), 0, stream>>>(qkvb, Vt);
    attn_kernel<<<dim3(1024), dim3(256), 0, stream>>>(qkvb, Vt, attb);
    gemm2ph_kernel<128, 128, 256, 2, 0><<<dim3(256), dim3(256), 0, stream>>>(
        attb, Woutt, bout, (void*)out, 4096, 1024, 1024, 8);
}